// Round 2
// baseline (2581.450 us; speedup 1.0000x reference)
//
#include <hip/hip_runtime.h>

// x: (64, 8192, 256) float32, cumsum along dim 1.
#define BATCH 64
#define LEN   8192
#define DIM   256
#define D4    64                 // float4 per row
#define SEGLEN 64                // rows per segment
#define NSEG  (LEN / SEGLEN)     // 128 segments per batch chain
#define NBLOCKS (BATCH * NSEG)   // 8192 blocks
#define CHUNKS 4
#define RPC   (SEGLEN / CHUNKS)  // 16 rows per chunk (held in registers)

#define FLAG_INVALID 0
#define FLAG_AGG     1
#define FLAG_INCL    2

__device__ __forceinline__ void f4_add(float4& a, const float4& v) {
    a.x += v.x; a.y += v.y; a.z += v.z; a.w += v.w;
}

// 16B payload as 2x 8B agent-scope atomics (reach the coherence point; immune
// to non-coherent per-XCD L2s).
__device__ __forceinline__ void atom_store_f4(float* p, float4 v) {
    union { float2 f; unsigned long long u; } a, b;
    a.f = make_float2(v.x, v.y); b.f = make_float2(v.z, v.w);
    unsigned long long* q = reinterpret_cast<unsigned long long*>(p);
    __hip_atomic_store(q + 0, a.u, __ATOMIC_RELAXED, __HIP_MEMORY_SCOPE_AGENT);
    __hip_atomic_store(q + 1, b.u, __ATOMIC_RELAXED, __HIP_MEMORY_SCOPE_AGENT);
}

__device__ __forceinline__ float4 atom_load_f4(const float* p) {
    const unsigned long long* q = reinterpret_cast<const unsigned long long*>(p);
    union { float2 f; unsigned long long u; } a, b;
    a.u = __hip_atomic_load(q + 0, __ATOMIC_RELAXED, __HIP_MEMORY_SCOPE_AGENT);
    b.u = __hip_atomic_load(q + 1, __ATOMIC_RELAXED, __HIP_MEMORY_SCOPE_AGENT);
    return make_float4(a.f.x, a.f.y, b.f.x, b.f.y);
}

__global__ __launch_bounds__(256, 4) void scan_lookback_kernel(
    const float* __restrict__ x, float* __restrict__ out,
    int* __restrict__ counter, int* __restrict__ flags)
{
    __shared__ float4 csum[CHUNKS][D4];  // per-chunk local sums
    __shared__ float4 pbuf[D4];          // global exclusive prefix broadcast
    __shared__ int vid_s;

    const int t = threadIdx.x;
    if (t == 0) vid_s = atomicAdd(counter, 1);   // dispatch-ordered virtual id
    __syncthreads();
    const int vid = vid_s;
    const int b = vid >> 7;          // vid / NSEG
    const int s = vid & (NSEG - 1);  // vid % NSEG

    const int l = t & 63;            // channel group (float4 within row)
    const int c = t >> 6;            // chunk (16 rows)

    const size_t segbase = ((size_t)b * LEN + (size_t)s * SEGLEN) * D4;
    const float4* xp = reinterpret_cast<const float4*>(x)
                     + segbase + (size_t)(c * RPC) * D4 + l;

    // Stream 16 rows into registers, reduce local sum.
    float4 v[RPC];
    float4 ls = make_float4(0.f, 0.f, 0.f, 0.f);
#pragma unroll
    for (int r = 0; r < RPC; ++r) {
        v[r] = xp[(size_t)r * D4];
        f4_add(ls, v[r]);
    }
    csum[c][l] = ls;
    __syncthreads();

    // Intra-block exclusive prefix over chunks (per thread).
    float4 ex = make_float4(0.f, 0.f, 0.f, 0.f);
#pragma unroll
    for (int cc = 0; cc < CHUNKS; ++cc)
        if (cc < c) f4_add(ex, csum[cc][l]);

    if (t < 64) {  // wave 0: aggregate post + lookback + inclusive post
        float4 agg = make_float4(0.f, 0.f, 0.f, 0.f);
#pragma unroll
        for (int cc = 0; cc < CHUNKS; ++cc) f4_add(agg, csum[cc][l]);

        int* flagp = flags + vid;
        const size_t aggrow  = segbase + (size_t)(SEGLEN - 2) * D4;  // stash
        const size_t inclrow = segbase + (size_t)(SEGLEN - 1) * D4;  // real out row

        float4 pref = make_float4(0.f, 0.f, 0.f, 0.f);
        if (s > 0) {
            // Post aggregate into out (temporarily, at 2nd-to-last row).
            atom_store_f4(out + (aggrow + l) * 4, agg);
            if (t == 0)
                __hip_atomic_store(flagp, FLAG_AGG, __ATOMIC_RELEASE, __HIP_MEMORY_SCOPE_AGENT);

            // Decoupled lookback over predecessors (descending j).
            int j = s - 1;
            while (j >= 0) {
                int* fj = flags + (vid - (s - j));  // = b*NSEG + j
                int f;
                while ((f = __hip_atomic_load(fj, __ATOMIC_ACQUIRE, __HIP_MEMORY_SCOPE_AGENT))
                       == FLAG_INVALID)
                    __builtin_amdgcn_s_sleep(1);
                const size_t jb = ((size_t)b * LEN + (size_t)j * SEGLEN) * D4;
                if (f == FLAG_AGG) {
                    float4 val = atom_load_f4(out + (jb + (size_t)(SEGLEN - 2) * D4 + l) * 4);
                    int f2 = __hip_atomic_load(fj, __ATOMIC_ACQUIRE, __HIP_MEMORY_SCOPE_AGENT);
                    if (f2 == FLAG_AGG) {  // re-check proves payload was pure agg
                        f4_add(pref, val);
                        --j;
                        continue;
                    }
                }
                // FLAG_INCL: inclusive prefix is the real output row.
                float4 val = atom_load_f4(out + (jb + (size_t)(SEGLEN - 1) * D4 + l) * 4);
                f4_add(pref, val);
                break;
            }
        }
        float4 incl = pref; f4_add(incl, agg);
        atom_store_f4(out + (inclrow + l) * 4, incl);
        if (t == 0)
            __hip_atomic_store(flagp, FLAG_INCL, __ATOMIC_RELEASE, __HIP_MEMORY_SCOPE_AGENT);
        __threadfence();  // order subsequent plain output stores after flag=2
        pbuf[l] = pref;
    }
    __syncthreads();

    // Emit final cumsum from registers.
    float4 acc = pbuf[l];
    f4_add(acc, ex);
    float4* op = reinterpret_cast<float4*>(out)
               + segbase + (size_t)(c * RPC) * D4 + l;
#pragma unroll
    for (int r = 0; r < RPC; ++r) {
        f4_add(acc, v[r]);
        op[(size_t)r * D4] = acc;
    }
}

// Fallback (never expected): one thread per (b,d) chain.
__global__ void serial_scan_kernel(const float* __restrict__ x, float* __restrict__ out) {
    const int b = blockIdx.x;
    const int d = threadIdx.x;
    const float* xp = x + (size_t)b * LEN * DIM + d;
    float*       op = out + (size_t)b * LEN * DIM + d;
    float acc = 0.f;
    for (int l = 0; l < LEN; ++l) {
        acc += xp[(size_t)l * DIM];
        op[(size_t)l * DIM] = acc;
    }
}

extern "C" void kernel_launch(void* const* d_in, const int* in_sizes, int n_in,
                              void* d_out, int out_size, void* d_ws, size_t ws_size,
                              hipStream_t stream) {
    const float* x = (const float*)d_in[0];
    float* out = (float*)d_out;

    const size_t need = 256 + (size_t)NBLOCKS * sizeof(int);  // counter + flags
    if (ws_size < need) {
        serial_scan_kernel<<<BATCH, DIM, 0, stream>>>(x, out);
        return;
    }
    int* counter = (int*)d_ws;
    int* flags   = (int*)d_ws + 64;  // 256 B offset
    hipMemsetAsync(d_ws, 0, need, stream);
    scan_lookback_kernel<<<NBLOCKS, 256, 0, stream>>>(x, out, counter, flags);
}

// Round 3
// 355.494 us; speedup vs baseline: 7.2616x; 7.2616x over previous
//
#include <hip/hip_runtime.h>

// x: (64, 8192, 256) float32, cumsum along dim 1.
#define BATCH 64
#define LEN   8192
#define DIM   256
#define D4    (DIM / 4)        // 64 float4 per row
#define Q     8                // channel slices per batch (one block each)
#define SF4   (D4 / Q)         // 8 float4 per slice (32 channels, 128 B/row)
#define TILE  64               // rows per tile
#define NT    (LEN / TILE)     // 128 tiles (serial per block, carry in regs)
#define GROUPS 32              // row-groups per tile (2 rows each)
#define LDS_PITCH 9            // pad 8 -> 9 float4: bank = 4*(g+f) mod 32, conflict-free

__device__ __forceinline__ void f4_add(float4& a, const float4& v) {
    a.x += v.x; a.y += v.y; a.z += v.z; a.w += v.w;
}

// One block owns the full 8192-row chain of a (batch, 32-channel slice).
// Serial over 128 tiles; carry lives in registers -> x read once, out written once.
__global__ __launch_bounds__(256, 2) void chained_scan_kernel(
    const float* __restrict__ x, float* __restrict__ out)
{
    __shared__ float4 gsum[GROUPS * LDS_PITCH];

    const int q = blockIdx.x;      // channel slice
    const int b = blockIdx.y;      // batch
    const int t = threadIdx.x;     // 0..255
    const int f = t & (SF4 - 1);   // f4 within slice: 0..7 (128 B contiguous per row-group)
    const int g = t >> 3;          // row-group within tile: 0..31 (2 rows each)

    const size_t chain = (size_t)b * LEN * D4 + (size_t)q * SF4 + f;
    const float4* xp = reinterpret_cast<const float4*>(x) + chain;
    float4*       op = reinterpret_cast<float4*>(out) + chain;
    const size_t r0 = (size_t)(g * 2) * D4;  // thread's first row offset within a tile

    float4 carry = make_float4(0.f, 0.f, 0.f, 0.f);

    // Prefetch tile 0.
    float4 a0 = xp[r0];
    float4 a1 = xp[r0 + D4];

    for (int tile = 0; tile < NT; ++tile) {
        // Issue next tile's loads first: HBM latency hides under this tile's work.
        float4 b0 = make_float4(0.f, 0.f, 0.f, 0.f);
        float4 b1 = b0;
        if (tile + 1 < NT) {
            const size_t nb = (size_t)(tile + 1) * TILE * D4 + r0;
            b0 = xp[nb];
            b1 = xp[nb + D4];
        }

        // 2-row local sum -> LDS.
        float4 ls = a0; f4_add(ls, a1);
        __syncthreads();                       // previous tile's gsum reads done
        gsum[g * LDS_PITCH + f] = ls;
        __syncthreads();

        // Per-thread scan over the 32 group sums (broadcast reads, conflict-free).
        float4 pref = make_float4(0.f, 0.f, 0.f, 0.f);
        float4 tot  = make_float4(0.f, 0.f, 0.f, 0.f);
#pragma unroll 8
        for (int j = 0; j < GROUPS; ++j) {
            float4 s = gsum[j * LDS_PITCH + f];
            if (j < g) f4_add(pref, s);        // predicated, no divergence cost
            f4_add(tot, s);
        }

        // Emit the two output rows, update register carry.
        const size_t o = (size_t)tile * TILE * D4 + r0;
        float4 o0 = carry; f4_add(o0, pref); f4_add(o0, a0);
        float4 o1 = o0;    f4_add(o1, a1);
        op[o]      = o0;
        op[o + D4] = o1;
        f4_add(carry, tot);

        a0 = b0; a1 = b1;
    }
}

extern "C" void kernel_launch(void* const* d_in, const int* in_sizes, int n_in,
                              void* d_out, int out_size, void* d_ws, size_t ws_size,
                              hipStream_t stream) {
    const float* x = (const float*)d_in[0];
    float* out = (float*)d_out;
    chained_scan_kernel<<<dim3(Q, BATCH), 256, 0, stream>>>(x, out);
}

// Round 4
// 226.092 us; speedup vs baseline: 11.4177x; 1.5723x over previous
//
#include <hip/hip_runtime.h>

// x: (64, 8192, 256) float32, cumsum along dim 1.
#define BATCH 64
#define LEN   8192
#define DIM   256
#define D4    (DIM / 4)        // 64 float4 per row
#define Q     8                // channel slices per batch (one block each)
#define SF4   (D4 / Q)         // 8 float4 per slice (32 channels, 128 B/row)
#define R     4                // rows per thread per tile
#define GROUPS 32              // row-groups per tile (256 threads / 8 f4)
#define TILE  (GROUPS * R)     // 128 rows per tile
#define NT    (LEN / TILE)     // 64 tiles, serial per block (carry in regs)

typedef float vf4 __attribute__((ext_vector_type(4)));

__device__ __forceinline__ void f4_add(float4& a, const float4& v) {
    a.x += v.x; a.y += v.y; a.z += v.z; a.w += v.w;
}

// One block owns the full 8192-row chain of a (batch, 32-channel slice).
// Serial over 64 tiles of 128 rows; carry in registers; x read once, out once.
// Tile scan: per-thread 4-row sum -> wave shfl-scan over 8 local groups ->
// tiny LDS exchange of 4 wave totals (double-buffered, 1 sync/tile).
__global__ __launch_bounds__(256, 2) void chained_scan_kernel(
    const float* __restrict__ x, float* __restrict__ out)
{
    __shared__ float4 wtot[2][4][SF4];   // [parity][wave][f4] = 1 KiB

    const int q    = blockIdx.x;         // channel slice
    const int b    = blockIdx.y;         // batch
    const int t    = threadIdx.x;        // 0..255
    const int f    = t & (SF4 - 1);      // f4 within slice (0..7)
    const int g    = t >> 3;             // group within tile (0..31), 4 rows each
    const int lane = t & 63;
    const int w    = t >> 6;             // wave 0..3
    const int lg   = lane >> 3;          // local group within wave (0..7)

    const size_t chain = (size_t)b * LEN * D4 + (size_t)q * SF4 + f;
    const float4* xp = reinterpret_cast<const float4*>(x) + chain;
    float4*       op = reinterpret_cast<float4*>(out) + chain;
    const size_t r0 = (size_t)(g * R) * D4;  // thread's first row offset in a tile

    float4 carry = make_float4(0.f, 0.f, 0.f, 0.f);

    // Prefetch tile 0.
    float4 a[R];
#pragma unroll
    for (int r = 0; r < R; ++r) a[r] = xp[r0 + (size_t)r * D4];

    for (int tile = 0; tile < NT; ++tile) {
        // Issue next tile's loads first; HBM latency hides under tile body.
        const int nxt = (tile + 1 < NT) ? tile + 1 : tile;
        const size_t nb = (size_t)nxt * TILE * D4 + r0;
        float4 nx[R];
#pragma unroll
        for (int r = 0; r < R; ++r) nx[r] = xp[nb + (size_t)r * D4];

        // 4-row group sum.
        float4 ls = a[0];
        f4_add(ls, a[1]); f4_add(ls, a[2]); f4_add(ls, a[3]);

        // Wave-inclusive scan over the 8 local groups (same-f lanes, stride 8).
        float4 incl = ls;
#pragma unroll
        for (int d = 1; d < 8; d <<= 1) {
            float4 o;
            o.x = __shfl_up(incl.x, d * 8, 64);
            o.y = __shfl_up(incl.y, d * 8, 64);
            o.z = __shfl_up(incl.z, d * 8, 64);
            o.w = __shfl_up(incl.w, d * 8, 64);
            if (lg >= d) f4_add(incl, o);
        }

        // Publish per-wave totals (local group 7 holds them), parity-buffered.
        const int par = tile & 1;
        if (lane >= 56) wtot[par][w][f] = incl;
        __syncthreads();

        // Cross-wave exclusive prefix + tile total (4 broadcast reads).
        float4 cross = make_float4(0.f, 0.f, 0.f, 0.f);
        float4 tot   = make_float4(0.f, 0.f, 0.f, 0.f);
#pragma unroll
        for (int ww = 0; ww < 4; ++ww) {
            float4 s = wtot[par][ww][f];
            if (ww < w) f4_add(cross, s);
            f4_add(tot, s);
        }

        // acc = carry + (exclusive prefix of this thread's group) = carry+cross+incl-ls
        float4 acc = carry;
        f4_add(acc, cross);
        f4_add(acc, incl);
        acc.x -= ls.x; acc.y -= ls.y; acc.z -= ls.z; acc.w -= ls.w;

        // Emit 4 output rows (nontemporal: out is never re-read; keep L3 for x).
        const size_t ob = (size_t)tile * TILE * D4 + r0;
#pragma unroll
        for (int r = 0; r < R; ++r) {
            f4_add(acc, a[r]);
            __builtin_nontemporal_store(*reinterpret_cast<const vf4*>(&acc),
                                        reinterpret_cast<vf4*>(op + ob + (size_t)r * D4));
        }

        f4_add(carry, tot);
#pragma unroll
        for (int r = 0; r < R; ++r) a[r] = nx[r];
    }
}

extern "C" void kernel_launch(void* const* d_in, const int* in_sizes, int n_in,
                              void* d_out, int out_size, void* d_ws, size_t ws_size,
                              hipStream_t stream) {
    const float* x = (const float*)d_in[0];
    float* out = (float*)d_out;
    chained_scan_kernel<<<dim3(Q, BATCH), 256, 0, stream>>>(x, out);
}